// Round 3
// baseline (562.833 us; speedup 1.0000x reference)
//
#include <hip/hip_runtime.h>
#include <math.h>

#define FIN 128
#define FOUT 64
#define MAXDEG 64

// ---------------- helpers ----------------

__device__ __forceinline__ float4 f4add(float4 a, float4 b) {
  return make_float4(a.x + b.x, a.y + b.y, a.z + b.z, a.w + b.w);
}
__device__ __forceinline__ float4 f4fma(float c, float4 v, float4 a) {
  return make_float4(fmaf(c, v.x, a.x), fmaf(c, v.y, a.y),
                     fmaf(c, v.z, a.z), fmaf(c, v.w, a.w));
}
__device__ __forceinline__ float4 f4shflxor(float4 v, int off) {
  return make_float4(__shfl_xor(v.x, off, 64), __shfl_xor(v.y, off, 64),
                     __shfl_xor(v.z, off, 64), __shfl_xor(v.w, off, 64));
}
__device__ __forceinline__ float red16(float v) {
  v += __shfl_xor(v, 1, 64);
  v += __shfl_xor(v, 2, 64);
  v += __shfl_xor(v, 4, 64);
  v += __shfl_xor(v, 8, 64);
  return v;
}

// logmap0 row factor: artanh(clip(n))/max(n,1e-15), c=1
__device__ __forceinline__ float row_scale(float ss) {
  float n  = sqrtf(ss);
  float nc = fmaxf(n, 1e-15f);
  float t  = fminf(nc, 1.0f - 1e-7f);
  float at = 0.5f * (log1pf(t) - log1pf(-t));
  return at / nc;
}

// ---------------- kernel 0: zero deg + transpose W (Wt[f][k] = Wup[k][f]) ----
__global__ __launch_bounds__(256) void k_pre(const float* __restrict__ Wup,
                                             float* __restrict__ Wt,
                                             int* __restrict__ deg, int N) {
  int tid = blockIdx.x * 256 + threadIdx.x;
  for (int i = tid; i < N; i += gridDim.x * 256) deg[i] = 0;
  if (blockIdx.x == 0) {
    for (int idx = threadIdx.x; idx < FIN * FOUT; idx += 256) {
      int k = idx >> 6, f = idx & 63;
      Wt[f * FIN + k] = Wup[idx];
    }
  }
}

// ---------------- kernel 1: logmap0 + GEMM(128->64) + leaky_relu ----------------
// lane = node. x row lives in 32xfloat4 registers; weights arrive as wave-
// uniform scalar loads (s_load) from the transposed Wt — no LDS, no conflicts,
// 1 SGPR operand per v_fma. 128-thread blocks for CU load balance.
__global__ __launch_bounds__(128) void k_gemm(const float* __restrict__ x,
                                              const float* __restrict__ Wt,
                                              float* __restrict__ u, int N) {
  int n = blockIdx.x * 128 + threadIdx.x;
  if (n >= N) return;
  const float4* xr = (const float4*)(x + (size_t)n * FIN);
  float4 a[32];
#pragma unroll
  for (int i = 0; i < 32; ++i) a[i] = xr[i];
  float ss = 0.f;
#pragma unroll
  for (int i = 0; i < 32; ++i) {
    ss = fmaf(a[i].x, a[i].x, ss); ss = fmaf(a[i].y, a[i].y, ss);
    ss = fmaf(a[i].z, a[i].z, ss); ss = fmaf(a[i].w, a[i].w, ss);
  }
  float sc = row_scale(ss);
  float4* uo = (float4*)(u + (size_t)n * FOUT);
#pragma unroll 1
  for (int f0 = 0; f0 < FOUT; f0 += 4) {
    const float* w0 = Wt + (size_t)(f0 + 0) * FIN;
    const float* w1 = Wt + (size_t)(f0 + 1) * FIN;
    const float* w2 = Wt + (size_t)(f0 + 2) * FIN;
    const float* w3 = Wt + (size_t)(f0 + 3) * FIN;
    float acc0 = 0.f, acc1 = 0.f, acc2 = 0.f, acc3 = 0.f;
#pragma unroll
    for (int i = 0; i < 32; ++i) {
      float4 av = a[i];
      acc0 = fmaf(av.x, w0[4*i], acc0); acc0 = fmaf(av.y, w0[4*i+1], acc0);
      acc0 = fmaf(av.z, w0[4*i+2], acc0); acc0 = fmaf(av.w, w0[4*i+3], acc0);
      acc1 = fmaf(av.x, w1[4*i], acc1); acc1 = fmaf(av.y, w1[4*i+1], acc1);
      acc1 = fmaf(av.z, w1[4*i+2], acc1); acc1 = fmaf(av.w, w1[4*i+3], acc1);
      acc2 = fmaf(av.x, w2[4*i], acc2); acc2 = fmaf(av.y, w2[4*i+1], acc2);
      acc2 = fmaf(av.z, w2[4*i+2], acc2); acc2 = fmaf(av.w, w2[4*i+3], acc2);
      acc3 = fmaf(av.x, w3[4*i], acc3); acc3 = fmaf(av.y, w3[4*i+1], acc3);
      acc3 = fmaf(av.z, w3[4*i+2], acc3); acc3 = fmaf(av.w, w3[4*i+3], acc3);
    }
    float v0 = sc * acc0, v1 = sc * acc1, v2 = sc * acc2, v3 = sc * acc3;
    v0 = (v0 >= 0.f) ? v0 : 0.01f * v0;
    v1 = (v1 >= 0.f) ? v1 : 0.01f * v1;
    v2 = (v2 >= 0.f) ? v2 : 0.01f * v2;
    v3 = (v3 >= 0.f) ? v3 : 0.01f * v3;
    uo[f0 >> 2] = make_float4(v0, v1, v2, v3);
  }
}

// ---------------- kernel 2: padded-CSR fill, 8 edges/thread ----------------
__global__ __launch_bounds__(256) void k_fill(const int* __restrict__ ei, int E,
                                              int* __restrict__ deg,
                                              int* __restrict__ slots) {
  int t = blockIdx.x * 256 + threadIdx.x;
  int e0 = t * 8;
  if (e0 + 7 < E && (E & 3) == 0) {
    int4 s0 = *(const int4*)(ei + e0);
    int4 s1 = *(const int4*)(ei + e0 + 4);
    int4 d0 = *(const int4*)(ei + E + e0);
    int4 d1 = *(const int4*)(ei + E + e0 + 4);
    int p0 = atomicAdd(&deg[d0.x], 1);
    int p1 = atomicAdd(&deg[d0.y], 1);
    int p2 = atomicAdd(&deg[d0.z], 1);
    int p3 = atomicAdd(&deg[d0.w], 1);
    int p4 = atomicAdd(&deg[d1.x], 1);
    int p5 = atomicAdd(&deg[d1.y], 1);
    int p6 = atomicAdd(&deg[d1.z], 1);
    int p7 = atomicAdd(&deg[d1.w], 1);
    if (p0 < MAXDEG) slots[(size_t)d0.x * MAXDEG + p0] = s0.x;
    if (p1 < MAXDEG) slots[(size_t)d0.y * MAXDEG + p1] = s0.y;
    if (p2 < MAXDEG) slots[(size_t)d0.z * MAXDEG + p2] = s0.z;
    if (p3 < MAXDEG) slots[(size_t)d0.w * MAXDEG + p3] = s0.w;
    if (p4 < MAXDEG) slots[(size_t)d1.x * MAXDEG + p4] = s1.x;
    if (p5 < MAXDEG) slots[(size_t)d1.y * MAXDEG + p5] = s1.y;
    if (p6 < MAXDEG) slots[(size_t)d1.z * MAXDEG + p6] = s1.z;
    if (p7 < MAXDEG) slots[(size_t)d1.w * MAXDEG + p7] = s1.w;
  } else {
    for (int j = 0; j < 8; ++j) {
      int e = e0 + j;
      if (e < E) {
        int s = ei[e], d = ei[E + e];
        int p = atomicAdd(&deg[d], 1);
        if (p < MAXDEG) slots[(size_t)d * MAXDEG + p] = s;
      }
    }
  }
}

// ---------------- agg kernels: 4 edges in parallel per wave ----------------
__global__ __launch_bounds__(256) void k_agg1(const int* __restrict__ deg,
                                              const int* __restrict__ slots,
                                              const float* __restrict__ u,
                                              const float* __restrict__ Wpl,
                                              float* __restrict__ sumn,
                                              float* __restrict__ selF, int N) {
  int wv = threadIdx.x >> 6, lane = threadIdx.x & 63;
  int i = blockIdx.x * 4 + wv;
  if (i >= N) return;
  int d = min(deg[i], MAXDEG);
  const int* sl = slots + (size_t)i * MAXDEG;
  int sub = lane >> 4, l4 = lane & 15;
  float4 acc0 = make_float4(0, 0, 0, 0), acc1 = make_float4(0, 0, 0, 0);
  for (int e = 0; e < d; e += 16) {
    int4 sv = ((const int4*)(sl + e))[sub];
    int base = e + sub * 4;
    float4 v0 = make_float4(0,0,0,0), v1 = v0, v2 = v0, v3 = v0;
    if (base < d)     v0 = ((const float4*)(u + (size_t)sv.x * 64))[l4];
    if (base + 1 < d) v1 = ((const float4*)(u + (size_t)sv.y * 64))[l4];
    if (base + 2 < d) v2 = ((const float4*)(u + (size_t)sv.z * 64))[l4];
    if (base + 3 < d) v3 = ((const float4*)(u + (size_t)sv.w * 64))[l4];
    acc0 = f4add(acc0, f4add(v0, v1));
    acc1 = f4add(acc1, f4add(v2, v3));
  }
  float4 acc = f4add(acc0, acc1);
  acc = f4add(acc, f4shflxor(acc, 16));
  acc = f4add(acc, f4shflxor(acc, 32));
  if (sub == 0) ((float4*)(sumn + (size_t)i * 64))[l4] = acc;
  int f = l4 * 4;
  float l0 = acc.x * Wpl[f * 2]       + acc.y * Wpl[(f + 1) * 2]
           + acc.z * Wpl[(f + 2) * 2] + acc.w * Wpl[(f + 3) * 2];
  float l1 = acc.x * Wpl[f * 2 + 1]       + acc.y * Wpl[(f + 1) * 2 + 1]
           + acc.z * Wpl[(f + 2) * 2 + 1] + acc.w * Wpl[(f + 3) * 2 + 1];
  l0 = red16(l0); l1 = red16(l1);
  float r0 = fmaxf(l0, 0.f), r1 = fmaxf(l1, 0.f);
  float m  = fmaxf(r0, r1);
  float e0 = expf(r0 - m), e1 = expf(r1 - m);
  float p1 = e1 / (e0 + e1);
  if (lane == 0) selF[i] = (p1 > 0.48f) ? 1.f : 0.f;
}

__global__ __launch_bounds__(256) void k_agg2(const int* __restrict__ deg,
                                              const int* __restrict__ slots,
                                              const float* __restrict__ u,
                                              const float* __restrict__ Wlw,
                                              const float* __restrict__ sumn,
                                              const float* __restrict__ selF,
                                              float* __restrict__ cF, int N) {
  int wv = threadIdx.x >> 6, lane = threadIdx.x & 63;
  int i = blockIdx.x * 4 + wv;
  if (i >= N) return;
  int d = min(deg[i], MAXDEG);
  const int* sl = slots + (size_t)i * MAXDEG;
  int sub = lane >> 4, l4 = lane & 15;
  float4 acc0 = make_float4(0, 0, 0, 0), acc1 = make_float4(0, 0, 0, 0);
  for (int e = 0; e < d; e += 16) {
    int4 sv = ((const int4*)(sl + e))[sub];
    int base = e + sub * 4;
    float g0 = 0.f, g1 = 0.f, g2 = 0.f, g3 = 0.f;
    if (base < d)     g0 = selF[sv.x];
    if (base + 1 < d) g1 = selF[sv.y];
    if (base + 2 < d) g2 = selF[sv.z];
    if (base + 3 < d) g3 = selF[sv.w];
    float4 v0 = make_float4(0,0,0,0), v1 = v0, v2 = v0, v3 = v0;
    if (g0 != 0.f) v0 = ((const float4*)(u + (size_t)sv.x * 64))[l4];
    if (g1 != 0.f) v1 = ((const float4*)(u + (size_t)sv.y * 64))[l4];
    if (g2 != 0.f) v2 = ((const float4*)(u + (size_t)sv.z * 64))[l4];
    if (g3 != 0.f) v3 = ((const float4*)(u + (size_t)sv.w * 64))[l4];
    acc0 = f4add(acc0, f4add(v0, v1));
    acc1 = f4add(acc1, f4add(v2, v3));
  }
  float4 acc = f4add(acc0, acc1);
  acc = f4add(acc, f4shflxor(acc, 16));
  acc = f4add(acc, f4shflxor(acc, 32));
  float4 sn = ((const float4*)(sumn + (size_t)i * 64))[l4];
  int f = l4 * 4;
  float t = acc.x * Wlw[f]     + acc.y * Wlw[f + 1]
          + acc.z * Wlw[f + 2] + acc.w * Wlw[f + 3]
          + sn.x * Wlw[64 + f]     + sn.y * Wlw[64 + f + 1]
          + sn.z * Wlw[64 + f + 2] + sn.w * Wlw[64 + f + 3];
  t = red16(t);
  float sig = 1.f / (1.f + expf(-t));
  if (lane == 0) cF[i] = (selF[i] != 0.f) ? sig : 0.f;
}

__global__ __launch_bounds__(256) void k_agg3(const int* __restrict__ deg,
                                              const int* __restrict__ slots,
                                              const float* __restrict__ u,
                                              const float* __restrict__ cF,
                                              float* __restrict__ out, int N) {
  int wv = threadIdx.x >> 6, lane = threadIdx.x & 63;
  int i = blockIdx.x * 4 + wv;
  if (i >= N) return;
  int d = min(deg[i], MAXDEG);
  const int* sl = slots + (size_t)i * MAXDEG;
  int sub = lane >> 4, l4 = lane & 15;
  float4 acc0 = make_float4(0, 0, 0, 0), acc1 = make_float4(0, 0, 0, 0);
  for (int e = 0; e < d; e += 16) {
    int4 sv = ((const int4*)(sl + e))[sub];
    int base = e + sub * 4;
    float c0 = 0.f, c1 = 0.f, c2 = 0.f, c3 = 0.f;
    if (base < d)     c0 = cF[sv.x];
    if (base + 1 < d) c1 = cF[sv.y];
    if (base + 2 < d) c2 = cF[sv.z];
    if (base + 3 < d) c3 = cF[sv.w];
    float4 v0 = make_float4(0,0,0,0), v1 = v0, v2 = v0, v3 = v0;
    if (c0 != 0.f) v0 = ((const float4*)(u + (size_t)sv.x * 64))[l4];
    if (c1 != 0.f) v1 = ((const float4*)(u + (size_t)sv.y * 64))[l4];
    if (c2 != 0.f) v2 = ((const float4*)(u + (size_t)sv.z * 64))[l4];
    if (c3 != 0.f) v3 = ((const float4*)(u + (size_t)sv.w * 64))[l4];
    acc0 = f4fma(c0, v0, acc0);
    acc0 = f4fma(c1, v1, acc0);
    acc1 = f4fma(c2, v2, acc1);
    acc1 = f4fma(c3, v3, acc1);
  }
  float4 acc = f4add(acc0, acc1);
  acc = f4add(acc, f4shflxor(acc, 16));
  acc = f4add(acc, f4shflxor(acc, 32));
  float4 uv = ((const float4*)(u + (size_t)i * 64))[l4];
  float4 ov = make_float4(uv.x + fmaxf(acc.x, 0.f), uv.y + fmaxf(acc.y, 0.f),
                          uv.z + fmaxf(acc.z, 0.f), uv.w + fmaxf(acc.w, 0.f));
  float ssp = ov.x * ov.x + ov.y * ov.y + ov.z * ov.z + ov.w * ov.w;
  float ss  = red16(ssp);
  float nc  = fmaxf(sqrtf(ss), 1e-15f);
  float th  = tanhf(nc);
  float fac = th / nc;
  float4 r = make_float4(ov.x * fac, ov.y * fac, ov.z * fac, ov.w * fac);
  float n2 = fmaxf(th, 1e-15f);
  float maxn = 1.0f - 4e-3f;
  float s = (n2 > maxn) ? (maxn / n2) : 1.0f;
  float4 res = make_float4(r.x * s, r.y * s, r.z * s, r.w * s);
  if (sub == 0) ((float4*)(out + (size_t)i * 64))[l4] = res;
}

// ---------------- launch ----------------
extern "C" void kernel_launch(void* const* d_in, const int* in_sizes, int n_in,
                              void* d_out, int out_size, void* d_ws, size_t ws_size,
                              hipStream_t stream) {
  const float* x   = (const float*)d_in[0];
  const int*   ei  = (const int*)d_in[1];
  const float* Wup = (const float*)d_in[2];
  const float* Wpl = (const float*)d_in[3];
  const float* Wlw = (const float*)d_in[4];
  float* out = (float*)d_out;

  int N = in_sizes[0] / FIN;     // 100000
  int E = in_sizes[1] / 2;       // 1600000

  char* ws = (char*)d_ws;
  float* u     = (float*)ws;                         // N*64 f32 = 25.6 MB
  float* sumn  = u + (size_t)N * 64;                 // 25.6 MB
  int*   slots = (int*)(sumn + (size_t)N * 64);      // N*64 i32 = 25.6 MB
  int*   deg   = slots + (size_t)N * MAXDEG;         // 0.4 MB
  float* selF  = (float*)(deg + N);                  // 0.4 MB
  float* cF    = selF + N;                           // 0.4 MB
  float* Wt    = cF + N;                             // 64*128 f32 = 32 KB

  k_pre<<<128, 256, 0, stream>>>(Wup, Wt, deg, N);
  k_gemm<<<(N + 127) / 128, 128, 0, stream>>>(x, Wt, u, N);
  k_fill<<<(E + 2047) / 2048, 256, 0, stream>>>(ei, E, deg, slots);
  int nblk = (N + 3) / 4;
  k_agg1<<<nblk, 256, 0, stream>>>(deg, slots, u, Wpl, sumn, selF, N);
  k_agg2<<<nblk, 256, 0, stream>>>(deg, slots, u, Wlw, sumn, selF, cF, N);
  k_agg3<<<nblk, 256, 0, stream>>>(deg, slots, u, cF, out, N);
}